// Round 10
// baseline (733.244 us; speedup 1.0000x reference)
//
#include <hip/hip_runtime.h>
#include <hip/hip_bf16.h>

#define N_NODES 100000
#define N_EDGES 300000
#define CH 256
#define EPS 1e-5f
#define AGG_BLOCKS 6250  // N_NODES / 16 exactly

typedef __hip_bfloat16 bf16;
typedef __attribute__((ext_vector_type(8))) short bf16x8_t;  // 8 bf16 (4 VGPRs)
typedef __attribute__((ext_vector_type(4))) float f32x4_t;   // 4 fp32 acc

__device__ __forceinline__ unsigned short f2bf(float f) {
    bf16 h = __float2bfloat16(f);
    return __builtin_bit_cast(unsigned short, h);
}
__device__ __forceinline__ float bf2f(unsigned short u) {
    unsigned int x = ((unsigned int)u) << 16;  // exact widening
    return __builtin_bit_cast(float, x);
}
__device__ __forceinline__ float bflo(unsigned int w) {
    return __builtin_bit_cast(float, w << 16);
}
__device__ __forceinline__ float bfhi(unsigned int w) {
    return __builtin_bit_cast(float, w & 0xffff0000u);
}
__device__ __forceinline__ void store4(bf16* p, float4 v) {
    ushort4 o; o.x = f2bf(v.x); o.y = f2bf(v.y); o.z = f2bf(v.z); o.w = f2bf(v.w);
    *(ushort4*)p = o;
}
__device__ __forceinline__ void store_val(bf16* p, float v) { *p = __float2bfloat16(v); }

__device__ __forceinline__ void async_copy16(const void* g, void* l) {
    __builtin_amdgcn_global_load_lds((const __attribute__((address_space(1))) void*)g,
                                     (__attribute__((address_space(3))) void*)l, 16, 0, 0);
}

// ================= CSR build =================
__global__ void k_zero_int(int* __restrict__ p, int n) {
    int i = blockIdx.x * 256 + threadIdx.x;
    if (i < n) p[i] = 0;
}
__global__ void k_count_deg(const int* __restrict__ dst, int* __restrict__ deg) {
    int e = blockIdx.x * 256 + threadIdx.x;
    if (e < N_EDGES) atomicAdd(&deg[dst[e]], 1);
}
__global__ void k_dinv_from_deg(const int* __restrict__ deg, float* __restrict__ dinv) {
    int i = blockIdx.x * 256 + threadIdx.x;
    if (i < N_NODES) dinv[i] = rsqrtf((float)(deg[i] + 1));  // +1 self loop
}
__global__ void k_block_sums(const int* __restrict__ deg, int* __restrict__ bsum) {
    __shared__ int s[256];
    int t = threadIdx.x;
    int i = blockIdx.x * 256 + t;
    s[t] = (i < N_NODES) ? deg[i] : 0;
    __syncthreads();
    for (int off = 128; off > 0; off >>= 1) {
        if (t < off) s[t] += s[t + off];
        __syncthreads();
    }
    if (t == 0) bsum[blockIdx.x] = s[0];
}
__global__ void k_scan_bsums(int* __restrict__ bsum, int nb) {
    __shared__ int s[512];
    int t = threadIdx.x;
    int v = (t < nb) ? bsum[t] : 0;
    s[t] = v;
    __syncthreads();
    for (int off = 1; off < 512; off <<= 1) {
        int u = (t >= off) ? s[t - off] : 0;
        __syncthreads();
        s[t] += u;
        __syncthreads();
    }
    if (t < nb) bsum[t] = s[t] - v;  // exclusive
}
__global__ void k_row_ptr(const int* __restrict__ deg, const int* __restrict__ bsum,
                          int* __restrict__ row_ptr) {
    __shared__ int s[256];
    int t = threadIdx.x;
    int i = blockIdx.x * 256 + t;
    int v = (i < N_NODES) ? deg[i] : 0;
    s[t] = v;
    __syncthreads();
    for (int off = 1; off < 256; off <<= 1) {
        int u = (t >= off) ? s[t - off] : 0;
        __syncthreads();
        s[t] += u;
        __syncthreads();
    }
    if (i < N_NODES) row_ptr[i] = bsum[blockIdx.x] + s[t] - v;  // exclusive
    if (blockIdx.x == 0 && t == 0) row_ptr[N_NODES] = N_EDGES;
}
__global__ void k_scatter(const int* __restrict__ src, const int* __restrict__ dst,
                          const int* __restrict__ row_ptr, int* __restrict__ cursor,
                          int* __restrict__ col) {
    int e = blockIdx.x * 256 + threadIdx.x;
    if (e < N_EDGES) {
        int d = dst[e];
        int p = atomicAdd(&cursor[d], 1);
        col[row_ptr[d] + p] = src[e];
    }
}

// ================= all weight transposes in one kernel =================
__global__ void k_transpose_all(const float* __restrict__ W1, const float* __restrict__ W2,
                                const float* __restrict__ W3, const float* __restrict__ fc1w,
                                bf16* __restrict__ wt) {
    int which = blockIdx.x >> 8;  // 0..4
    int idx = ((blockIdx.x & 255) << 8) + threadIdx.x;
    int n = idx >> 8, k = idx & 255;
    const float* W; int ro = 0;
    switch (which) {
        case 0: W = W1; break;
        case 1: W = W2; break;
        case 2: W = W3; break;
        case 3: W = fc1w; break;
        default: W = fc1w; ro = 256; break;
    }
    wt[(size_t)which * 65536 + (size_t)n * 256 + k] =
        __float2bfloat16(W[(size_t)(ro + k) * 256 + n]);
}

// ====== MFMA GEMM with VGPR-staged A (fused cast / BN+relu): C = f(A) @ Bt^T ======
// FP32A: A is fp32 (layer 1, cast fused). BN: apply relu(a*scale+shift) (layers 2,3).
// B staged async. 128x128 tile, BK=64, ldc=256, N=256 (grid.x=2).
template <bool FP32A, bool BN>
__global__ __launch_bounds__(256) void k_gemm_stageA(const void* __restrict__ Araw,
                                                     const bf16* __restrict__ Bt,
                                                     bf16* __restrict__ C, int M,
                                                     const float* __restrict__ scale,
                                                     const float* __restrict__ shift) {
    __shared__ bf16 As[128 * 64];
    __shared__ bf16 Bs[128 * 64];
    const int tid = threadIdx.x;
    const int lane = tid & 63;
    const int w = tid >> 6;
    const int wr = w >> 1, wc = w & 1;
    const int lr = lane & 15, quad = lane >> 4;
    const int row0 = blockIdx.y * 128;
    const int col0 = blockIdx.x * 128;

    f32x4_t acc[4][4] = {};

    for (int k0 = 0; k0 < 256; k0 += 64) {
        // B: async direct-to-LDS
#pragma unroll
        for (int i = 0; i < 4; ++i) {
            int j = i * 256 + tid;
            int r = j >> 3, c = j & 7;
            int gk = ((c ^ (r & 7)) << 3);
            async_copy16(Bt + (size_t)(col0 + r) * 256 + k0 + gk, (void*)(Bs + j * 8));
        }
        // A: VGPR load + transform + ds_write
#pragma unroll
        for (int i = 0; i < 4; ++i) {
            int j = i * 256 + tid;
            int r = j >> 3, c = j & 7;
            int gk = ((c ^ (r & 7)) << 3);
            int gr = row0 + r; gr = gr < M ? gr : M - 1;
            float f[8];
            if (FP32A) {
                const float* Af = (const float*)Araw + (size_t)gr * 256 + k0 + gk;
                float4 a0 = *(const float4*)Af;
                float4 a1 = *(const float4*)(Af + 4);
                f[0] = a0.x; f[1] = a0.y; f[2] = a0.z; f[3] = a0.w;
                f[4] = a1.x; f[5] = a1.y; f[6] = a1.z; f[7] = a1.w;
            } else {
                const unsigned short* Ab = (const unsigned short*)Araw + (size_t)gr * 256 + k0 + gk;
                uint4 raw = *(const uint4*)Ab;
                f[0] = bflo(raw.x); f[1] = bfhi(raw.x);
                f[2] = bflo(raw.y); f[3] = bfhi(raw.y);
                f[4] = bflo(raw.z); f[5] = bfhi(raw.z);
                f[6] = bflo(raw.w); f[7] = bfhi(raw.w);
            }
            if (BN) {
                float4 sc0 = *(const float4*)(scale + k0 + gk);
                float4 sc1 = *(const float4*)(scale + k0 + gk + 4);
                float4 sh0 = *(const float4*)(shift + k0 + gk);
                float4 sh1 = *(const float4*)(shift + k0 + gk + 4);
                f[0] = fmaxf(f[0] * sc0.x + sh0.x, 0.f);
                f[1] = fmaxf(f[1] * sc0.y + sh0.y, 0.f);
                f[2] = fmaxf(f[2] * sc0.z + sh0.z, 0.f);
                f[3] = fmaxf(f[3] * sc0.w + sh0.w, 0.f);
                f[4] = fmaxf(f[4] * sc1.x + sh1.x, 0.f);
                f[5] = fmaxf(f[5] * sc1.y + sh1.y, 0.f);
                f[6] = fmaxf(f[6] * sc1.z + sh1.z, 0.f);
                f[7] = fmaxf(f[7] * sc1.w + sh1.w, 0.f);
            }
            bf16x8_t pk;
#pragma unroll
            for (int e = 0; e < 8; ++e) pk[e] = (short)f2bf(f[e]);
            *(bf16x8_t*)(As + j * 8) = pk;
        }
        __syncthreads();
#pragma unroll
        for (int ks = 0; ks < 2; ++ks) {
            bf16x8_t af[4], bfr[4];
#pragma unroll
            for (int mi = 0; mi < 4; ++mi) {
                int m = wr * 64 + mi * 16 + lr;
                int c = (ks * 4 + quad) ^ (m & 7);
                af[mi] = *(const bf16x8_t*)(As + m * 64 + c * 8);
            }
#pragma unroll
            for (int ni = 0; ni < 4; ++ni) {
                int n = wc * 64 + ni * 16 + lr;
                int c = (ks * 4 + quad) ^ (n & 7);
                bfr[ni] = *(const bf16x8_t*)(Bs + n * 64 + c * 8);
            }
#pragma unroll
            for (int mi = 0; mi < 4; ++mi)
#pragma unroll
                for (int ni = 0; ni < 4; ++ni)
                    acc[mi][ni] = __builtin_amdgcn_mfma_f32_16x16x32_bf16(
                        af[mi], bfr[ni], acc[mi][ni], 0, 0, 0);
        }
        __syncthreads();
    }
#pragma unroll
    for (int mi = 0; mi < 4; ++mi) {
#pragma unroll
        for (int r = 0; r < 4; ++r) {
            int row = row0 + wr * 64 + mi * 16 + quad * 4 + r;
            if (row < M) {
#pragma unroll
                for (int ni = 0; ni < 4; ++ni) {
                    int colg = col0 + wc * 64 + ni * 16 + lr;
                    store_val(C + (size_t)row * 256 + colg, acc[mi][ni][r]);
                }
            }
        }
    }
}

// ========== plain async-A MFMA GEMM (UV): C = A @ Bt^T, + bias on cols<256 ==========
__global__ __launch_bounds__(256) void k_gemm_mfma(const bf16* __restrict__ A,
                                                   const bf16* __restrict__ Bt,
                                                   bf16* __restrict__ C, int M, int ldc,
                                                   const float* __restrict__ bias256) {
    __shared__ bf16 As[128 * 64];
    __shared__ bf16 Bs[128 * 64];
    const int tid = threadIdx.x;
    const int lane = tid & 63;
    const int w = tid >> 6;
    const int wr = w >> 1, wc = w & 1;
    const int lr = lane & 15, quad = lane >> 4;
    const int row0 = blockIdx.y * 128;
    const int col0 = blockIdx.x * 128;

    f32x4_t acc[4][4] = {};

    for (int k0 = 0; k0 < 256; k0 += 64) {
#pragma unroll
        for (int i = 0; i < 4; ++i) {
            int j = i * 256 + tid;
            int r = j >> 3, c = j & 7;
            int gk = ((c ^ (r & 7)) << 3);
            int gr = row0 + r; gr = gr < M ? gr : M - 1;
            async_copy16(A + (size_t)gr * 256 + k0 + gk, (void*)(As + j * 8));
            async_copy16(Bt + (size_t)(col0 + r) * 256 + k0 + gk, (void*)(Bs + j * 8));
        }
        __syncthreads();
#pragma unroll
        for (int ks = 0; ks < 2; ++ks) {
            bf16x8_t af[4], bfr[4];
#pragma unroll
            for (int mi = 0; mi < 4; ++mi) {
                int m = wr * 64 + mi * 16 + lr;
                int c = (ks * 4 + quad) ^ (m & 7);
                af[mi] = *(const bf16x8_t*)(As + m * 64 + c * 8);
            }
#pragma unroll
            for (int ni = 0; ni < 4; ++ni) {
                int n = wc * 64 + ni * 16 + lr;
                int c = (ks * 4 + quad) ^ (n & 7);
                bfr[ni] = *(const bf16x8_t*)(Bs + n * 64 + c * 8);
            }
#pragma unroll
            for (int mi = 0; mi < 4; ++mi)
#pragma unroll
                for (int ni = 0; ni < 4; ++ni)
                    acc[mi][ni] = __builtin_amdgcn_mfma_f32_16x16x32_bf16(
                        af[mi], bfr[ni], acc[mi][ni], 0, 0, 0);
        }
        __syncthreads();
    }
    // per-thread bias values for the 4 ni column positions (0 if col >= 256)
    float bv[4];
#pragma unroll
    for (int ni = 0; ni < 4; ++ni) {
        int colg = col0 + wc * 64 + ni * 16 + lr;
        bv[ni] = (colg < 256) ? bias256[colg] : 0.f;
    }
#pragma unroll
    for (int mi = 0; mi < 4; ++mi) {
#pragma unroll
        for (int r = 0; r < 4; ++r) {
            int row = row0 + wr * 64 + mi * 16 + quad * 4 + r;
            if (row < M) {
#pragma unroll
                for (int ni = 0; ni < 4; ++ni) {
                    int colg = col0 + wc * 64 + ni * 16 + lr;
                    store_val(C + (size_t)row * ldc + colg, acc[mi][ni][r] + bv[ni]);
                }
            }
        }
    }
}

// ===== CSR aggregation, 16 nodes/block (4/wave), optional fused BN partial stats =====
// STATS: part[blockIdx][c] = sum over block's 16 nodes (c<256: sum; c>=256: sumsq), fp32.
template <bool STATS>
__global__ __launch_bounds__(256) void k_agg_csr(const unsigned short* __restrict__ xw,
                                                 const float* __restrict__ dinv,
                                                 const int* __restrict__ row_ptr,
                                                 const int* __restrict__ col,
                                                 const float* __restrict__ bias,
                                                 bf16* __restrict__ out,
                                                 float* __restrict__ part) {
    __shared__ float sred[4][256];
    __shared__ float qred[4][256];
    int w = threadIdx.x >> 6, lane = threadIdx.x & 63;
    int base = blockIdx.x * 16 + w * 4;  // exact: AGG_BLOCKS*16 == N_NODES
    const ushort4* xwv = (const ushort4*)xw;
    float4 bv = ((const float4*)bias)[lane];
    float4 s4 = make_float4(0.f, 0.f, 0.f, 0.f);
    float4 q4 = make_float4(0.f, 0.f, 0.f, 0.f);
#pragma unroll
    for (int n = 0; n < 4; ++n) {
        int node = base + n;
        int beg = row_ptr[node], end = row_ptr[node + 1];
        float dv = dinv[node];
        ushort4 xr = xwv[(size_t)node * 64 + lane];
        float s2 = dv * dv;
        float4 acc;
        acc.x = s2 * bf2f(xr.x); acc.y = s2 * bf2f(xr.y);
        acc.z = s2 * bf2f(xr.z); acc.w = s2 * bf2f(xr.w);
        for (int i = beg; i < end; ++i) {
            int s = col[i];
            float wgt = dv * dinv[s];
            ushort4 m = xwv[(size_t)s * 64 + lane];
            acc.x += wgt * bf2f(m.x); acc.y += wgt * bf2f(m.y);
            acc.z += wgt * bf2f(m.z); acc.w += wgt * bf2f(m.w);
        }
        acc.x += bv.x; acc.y += bv.y; acc.z += bv.z; acc.w += bv.w;
        store4(out + (size_t)node * CH + lane * 4, acc);
        if (STATS) {
            s4.x += acc.x; s4.y += acc.y; s4.z += acc.z; s4.w += acc.w;
            q4.x += acc.x * acc.x; q4.y += acc.y * acc.y;
            q4.z += acc.z * acc.z; q4.w += acc.w * acc.w;
        }
    }
    if (STATS) {
        *(float4*)(&sred[w][lane * 4]) = s4;
        *(float4*)(&qred[w][lane * 4]) = q4;
        __syncthreads();
        if (w == 0) {
#pragma unroll
            for (int g = 1; g < 4; ++g) {
                float4 sg = *(float4*)(&sred[g][lane * 4]);
                float4 qg = *(float4*)(&qred[g][lane * 4]);
                s4.x += sg.x; s4.y += sg.y; s4.z += sg.z; s4.w += sg.w;
                q4.x += qg.x; q4.y += qg.y; q4.z += qg.z; q4.w += qg.w;
            }
            float* p = part + (size_t)blockIdx.x * 512;
            *(float4*)(p + lane * 4) = s4;
            *(float4*)(p + 256 + lane * 4) = q4;
        }
    }
}

// one wave per channel: lanes stride over AGG_BLOCKS partials, shuffle-reduce
__global__ __launch_bounds__(256) void k_bn_finalize(const float* __restrict__ part,
                                                     const float* __restrict__ g,
                                                     const float* __restrict__ be,
                                                     float* __restrict__ scale,
                                                     float* __restrict__ shift) {
    int wave = threadIdx.x >> 6, lane = threadIdx.x & 63;
    int c = blockIdx.x * 4 + wave;  // 0..255
    float s = 0.f, q = 0.f;
    for (int j = lane; j < AGG_BLOCKS; j += 64) {
        s += part[(size_t)j * 512 + c];
        q += part[(size_t)j * 512 + 256 + c];
    }
#pragma unroll
    for (int off = 32; off > 0; off >>= 1) {
        s += __shfl_down(s, off, 64);
        q += __shfl_down(q, off, 64);
    }
    if (lane == 0) {
        float mu = s * (1.0f / N_NODES);
        float var = q * (1.0f / N_NODES) - mu * mu;
        float sc = g[c] * rsqrtf(var + EPS);
        scale[c] = sc;
        shift[c] = be[c] - mu * sc;
    }
}

// ======= edge scoring: 2 edges/wave, 32 lanes each, 8 ch/lane; fc1_b pre-added to u =======
__global__ __launch_bounds__(256) void k_edge_score(
        const unsigned short* __restrict__ uv,
        const int* __restrict__ src, const int* __restrict__ dst,
        const int* __restrict__ neg,
        const float* __restrict__ fc2_w, const float* __restrict__ fc2_b,
        float* __restrict__ out) {
    int wave = threadIdx.x >> 6, lane = threadIdx.x & 63;
    int half = lane >> 5, l = lane & 31;
    int e = blockIdx.x * 8 + wave * 2 + half;
    if (e >= N_EDGES) return;
    int s = src[e], d = dst[e], g = neg[e];
    uint4 uu = ((const uint4*)(uv + (size_t)s * 512))[l];
    uint4 vp = ((const uint4*)(uv + (size_t)d * 512 + 256))[l];
    uint4 vn = ((const uint4*)(uv + (size_t)g * 512 + 256))[l];
    float4 w0 = ((const float4*)fc2_w)[l * 2];
    float4 w1 = ((const float4*)fc2_w)[l * 2 + 1];

    float t0 = bflo(uu.x), t1 = bfhi(uu.x);
    float t2 = bflo(uu.y), t3 = bfhi(uu.y);
    float t4 = bflo(uu.z), t5 = bfhi(uu.z);
    float t6 = bflo(uu.w), t7 = bfhi(uu.w);

    float accp = fmaxf(t0 + bflo(vp.x), 0.f) * w0.x + fmaxf(t1 + bfhi(vp.x), 0.f) * w0.y +
                 fmaxf(t2 + bflo(vp.y), 0.f) * w0.z + fmaxf(t3 + bfhi(vp.y), 0.f) * w0.w +
                 fmaxf(t4 + bflo(vp.z), 0.f) * w1.x + fmaxf(t5 + bfhi(vp.z), 0.f) * w1.y +
                 fmaxf(t6 + bflo(vp.w), 0.f) * w1.z + fmaxf(t7 + bfhi(vp.w), 0.f) * w1.w;
    float accn = fmaxf(t0 + bflo(vn.x), 0.f) * w0.x + fmaxf(t1 + bfhi(vn.x), 0.f) * w0.y +
                 fmaxf(t2 + bflo(vn.y), 0.f) * w0.z + fmaxf(t3 + bfhi(vn.y), 0.f) * w0.w +
                 fmaxf(t4 + bflo(vn.z), 0.f) * w1.x + fmaxf(t5 + bfhi(vn.z), 0.f) * w1.y +
                 fmaxf(t6 + bflo(vn.w), 0.f) * w1.z + fmaxf(t7 + bfhi(vn.w), 0.f) * w1.w;
#pragma unroll
    for (int off = 16; off > 0; off >>= 1) {
        accp += __shfl_down(accp, off, 64);
        accn += __shfl_down(accn, off, 64);
    }
    if (l == 0) {
        float bb = fc2_b[0];
        out[e] = 1.0f / (1.0f + expf(-(accp + bb)));
        out[N_EDGES + e] = 1.0f / (1.0f + expf(-(accn + bb)));
    }
}

extern "C" void kernel_launch(void* const* d_in, const int* in_sizes, int n_in,
                              void* d_out, int out_size, void* d_ws, size_t ws_size,
                              hipStream_t stream) {
    const float* node_feat = (const float*)d_in[0];
    const int* src = (const int*)d_in[1];
    const int* dst = (const int*)d_in[2];
    const int* neg = (const int*)d_in[3];
    const float* W1 = (const float*)d_in[4];  const float* b1 = (const float*)d_in[5];
    const float* W2 = (const float*)d_in[6];  const float* b2 = (const float*)d_in[7];
    const float* W3 = (const float*)d_in[8];  const float* b3 = (const float*)d_in[9];
    const float* g1 = (const float*)d_in[10]; const float* be1 = (const float*)d_in[11];
    const float* g2 = (const float*)d_in[12]; const float* be2 = (const float*)d_in[13];
    const float* fc1_w = (const float*)d_in[14]; const float* fc1_b = (const float*)d_in[15];
    const float* fc2_w = (const float*)d_in[16]; const float* fc2_b = (const float*)d_in[17];
    float* out = (float*)d_out;

    // ---- workspace layout (~221 MB total) ----
    const size_t NF = (size_t)N_NODES * CH;  // 25,600,000
    bf16* UV = (bf16*)d_ws;                  // [node][512] u|v (2*NF)
    bf16* Xbf = UV + 2 * NF;                 // bf16 agg output / z (NF)
    bf16* XwBf = Xbf + NF;                   // bf16 GEMM output xw (NF)
    bf16* wt = XwBf + NF;                    // 5 * 65536 (wt1,wt2,wt3,wtu,wtv)
    float* dinv = (float*)(wt + 5 * 65536);
    float* bnpart = dinv + N_NODES;          // AGG_BLOCKS * 512 (12.8 MB)
    float* scale = bnpart + (size_t)AGG_BLOCKS * 512;
    float* shift = scale + CH;
    int* ideg = (int*)(shift + CH);          // N (cursor follows: zeroed together)
    int* cursor = ideg + N_NODES;
    int* row_ptr = cursor + N_NODES;
    int* col = row_ptr + N_NODES + 1;
    int* bsum = col + N_EDGES;               // 512
    (void)ws_size;

    dim3 gemmGrid(2, (N_NODES + 127) / 128);   // 2 x 782
    dim3 uvGrid(4, (N_NODES + 127) / 128);     // 4 x 782 (N=512)
    int nodeBlocks = (N_NODES + 255) / 256;    // 391
    int edgeBlocks = (N_EDGES + 255) / 256;
    int scoreBlocks = (N_EDGES + 7) / 8;       // 37500

    // ---- CSR build + dinv ----
    k_zero_int<<<(2 * N_NODES + 255) / 256, 256, 0, stream>>>(ideg, 2 * N_NODES);
    k_count_deg<<<edgeBlocks, 256, 0, stream>>>(dst, ideg);
    k_dinv_from_deg<<<nodeBlocks, 256, 0, stream>>>(ideg, dinv);
    k_block_sums<<<nodeBlocks, 256, 0, stream>>>(ideg, bsum);
    k_scan_bsums<<<1, 512, 0, stream>>>(bsum, nodeBlocks);
    k_row_ptr<<<nodeBlocks, 256, 0, stream>>>(ideg, bsum, row_ptr);
    k_scatter<<<edgeBlocks, 256, 0, stream>>>(src, dst, row_ptr, cursor, col);

    // ---- all weight transposes ----
    k_transpose_all<<<1280, 256, 0, stream>>>(W1, W2, W3, fc1_w, wt);

    // ---- layer 1 (fp32 A cast fused into staging) ----
    k_gemm_stageA<true, false><<<gemmGrid, 256, 0, stream>>>(node_feat, wt, XwBf, N_NODES,
                                                             nullptr, nullptr);
    k_agg_csr<true><<<AGG_BLOCKS, 256, 0, stream>>>((unsigned short*)XwBf, dinv, row_ptr,
                                                    col, b1, Xbf, bnpart);
    k_bn_finalize<<<64, 256, 0, stream>>>(bnpart, g1, be1, scale, shift);

    // ---- layer 2 (BN1+relu fused into A staging) ----
    k_gemm_stageA<false, true><<<gemmGrid, 256, 0, stream>>>(Xbf, wt + 65536, XwBf, N_NODES,
                                                             scale, shift);
    k_agg_csr<true><<<AGG_BLOCKS, 256, 0, stream>>>((unsigned short*)XwBf, dinv, row_ptr,
                                                    col, b2, Xbf, bnpart);
    k_bn_finalize<<<64, 256, 0, stream>>>(bnpart, g2, be2, scale, shift);

    // ---- layer 3 (BN2+relu fused into A staging; z -> Xbf) ----
    k_gemm_stageA<false, true><<<gemmGrid, 256, 0, stream>>>(Xbf, wt + 2 * 65536, XwBf,
                                                             N_NODES, scale, shift);
    k_agg_csr<false><<<AGG_BLOCKS, 256, 0, stream>>>((unsigned short*)XwBf, dinv, row_ptr,
                                                     col, b3, Xbf, nullptr);

    // ---- link predictor: UV = z @ [wtu|wtv]^T + [fc1_b|0] ----
    k_gemm_mfma<<<uvGrid, 256, 0, stream>>>(Xbf, wt + 3 * 65536, UV, N_NODES, 512, fc1_b);
    k_edge_score<<<scoreBlocks, 256, 0, stream>>>((unsigned short*)UV, src, dst, neg,
                                                  fc2_w, fc2_b, out);
}

// Round 11
// 699.258 us; speedup vs baseline: 1.0486x; 1.0486x over previous
//
#include <hip/hip_runtime.h>
#include <hip/hip_bf16.h>

#define N_NODES 100000
#define N_EDGES 300000
#define CH 256
#define EPS 1e-5f
#define AGG_BLOCKS 6250  // N_NODES / 16 exactly

typedef __hip_bfloat16 bf16;
typedef __attribute__((ext_vector_type(8))) short bf16x8_t;  // 8 bf16 (4 VGPRs)
typedef __attribute__((ext_vector_type(4))) float f32x4_t;   // 4 fp32 acc

__device__ __forceinline__ unsigned short f2bf(float f) {
    bf16 h = __float2bfloat16(f);
    return __builtin_bit_cast(unsigned short, h);
}
__device__ __forceinline__ float bf2f(unsigned short u) {
    unsigned int x = ((unsigned int)u) << 16;  // exact widening
    return __builtin_bit_cast(float, x);
}
__device__ __forceinline__ float bflo(unsigned int w) {
    return __builtin_bit_cast(float, w << 16);
}
__device__ __forceinline__ float bfhi(unsigned int w) {
    return __builtin_bit_cast(float, w & 0xffff0000u);
}
__device__ __forceinline__ void store4(bf16* p, float4 v) {
    ushort4 o; o.x = f2bf(v.x); o.y = f2bf(v.y); o.z = f2bf(v.z); o.w = f2bf(v.w);
    *(ushort4*)p = o;
}
__device__ __forceinline__ void store_val(bf16* p, float v) { *p = __float2bfloat16(v); }

__device__ __forceinline__ void async_copy16(const void* g, void* l) {
    __builtin_amdgcn_global_load_lds((const __attribute__((address_space(1))) void*)g,
                                     (__attribute__((address_space(3))) void*)l, 16, 0, 0);
}

// ================= CSR build =================
__global__ void k_zero_int(int* __restrict__ p, int n) {
    int i = blockIdx.x * 256 + threadIdx.x;
    if (i < n) p[i] = 0;
}
__global__ void k_count_deg(const int* __restrict__ dst, int* __restrict__ deg) {
    int e = blockIdx.x * 256 + threadIdx.x;
    if (e < N_EDGES) atomicAdd(&deg[dst[e]], 1);
}
__global__ void k_dinv_from_deg(const int* __restrict__ deg, float* __restrict__ dinv) {
    int i = blockIdx.x * 256 + threadIdx.x;
    if (i < N_NODES) dinv[i] = rsqrtf((float)(deg[i] + 1));  // +1 self loop
}
__global__ void k_block_sums(const int* __restrict__ deg, int* __restrict__ bsum) {
    __shared__ int s[256];
    int t = threadIdx.x;
    int i = blockIdx.x * 256 + t;
    s[t] = (i < N_NODES) ? deg[i] : 0;
    __syncthreads();
    for (int off = 128; off > 0; off >>= 1) {
        if (t < off) s[t] += s[t + off];
        __syncthreads();
    }
    if (t == 0) bsum[blockIdx.x] = s[0];
}
__global__ void k_scan_bsums(int* __restrict__ bsum, int nb) {
    __shared__ int s[512];
    int t = threadIdx.x;
    int v = (t < nb) ? bsum[t] : 0;
    s[t] = v;
    __syncthreads();
    for (int off = 1; off < 512; off <<= 1) {
        int u = (t >= off) ? s[t - off] : 0;
        __syncthreads();
        s[t] += u;
        __syncthreads();
    }
    if (t < nb) bsum[t] = s[t] - v;  // exclusive
}
__global__ void k_row_ptr(const int* __restrict__ deg, const int* __restrict__ bsum,
                          int* __restrict__ row_ptr) {
    __shared__ int s[256];
    int t = threadIdx.x;
    int i = blockIdx.x * 256 + t;
    int v = (i < N_NODES) ? deg[i] : 0;
    s[t] = v;
    __syncthreads();
    for (int off = 1; off < 256; off <<= 1) {
        int u = (t >= off) ? s[t - off] : 0;
        __syncthreads();
        s[t] += u;
        __syncthreads();
    }
    if (i < N_NODES) row_ptr[i] = bsum[blockIdx.x] + s[t] - v;  // exclusive
    if (blockIdx.x == 0 && t == 0) row_ptr[N_NODES] = N_EDGES;
}
// scatter also precomputes per-edge weight wedge = dinv[d]*dinv[s]
__global__ void k_scatter(const int* __restrict__ src, const int* __restrict__ dst,
                          const int* __restrict__ row_ptr, int* __restrict__ cursor,
                          const float* __restrict__ dinv,
                          int* __restrict__ col, float* __restrict__ wedge) {
    int e = blockIdx.x * 256 + threadIdx.x;
    if (e < N_EDGES) {
        int d = dst[e], s = src[e];
        int p = atomicAdd(&cursor[d], 1);
        int idx = row_ptr[d] + p;
        col[idx] = s;
        wedge[idx] = dinv[d] * dinv[s];
    }
}

// ================= all weight transposes in one kernel =================
__global__ void k_transpose_all(const float* __restrict__ W1, const float* __restrict__ W2,
                                const float* __restrict__ W3, const float* __restrict__ fc1w,
                                bf16* __restrict__ wt) {
    int which = blockIdx.x >> 8;  // 0..4
    int idx = ((blockIdx.x & 255) << 8) + threadIdx.x;
    int n = idx >> 8, k = idx & 255;
    const float* W; int ro = 0;
    switch (which) {
        case 0: W = W1; break;
        case 1: W = W2; break;
        case 2: W = W3; break;
        case 3: W = fc1w; break;
        default: W = fc1w; ro = 256; break;
    }
    wt[(size_t)which * 65536 + (size_t)n * 256 + k] =
        __float2bfloat16(W[(size_t)(ro + k) * 256 + n]);
}

// ================= casts =================
__global__ void k_cast_bf16_v4(const float* __restrict__ x, unsigned short* __restrict__ y) {
    int i = blockIdx.x * 256 + threadIdx.x;  // over NF/4
    float4 v = ((const float4*)x)[i];
    ushort4 o;
    o.x = f2bf(v.x); o.y = f2bf(v.y); o.z = f2bf(v.z); o.w = f2bf(v.w);
    ((ushort4*)y)[i] = o;
}
// in-place BN apply + relu on bf16 buffer
__global__ void k_bn_relu_bf16(unsigned short* __restrict__ x, const float* __restrict__ scale,
                               const float* __restrict__ shift) {
    int i = blockIdx.x * 256 + threadIdx.x;  // over NF/4
    ushort4 m = ((ushort4*)x)[i];
    int c = (i & 63) * 4;
    float4 sc = *(const float4*)(scale + c);
    float4 sh = *(const float4*)(shift + c);
    ushort4 o;
    o.x = f2bf(fmaxf(bf2f(m.x) * sc.x + sh.x, 0.f));
    o.y = f2bf(fmaxf(bf2f(m.y) * sc.y + sh.y, 0.f));
    o.z = f2bf(fmaxf(bf2f(m.z) * sc.z + sh.z, 0.f));
    o.w = f2bf(fmaxf(bf2f(m.w) * sc.w + sh.w, 0.f));
    ((ushort4*)x)[i] = o;
}

// ====== bf16 MFMA GEMM (async staged): C[M x N] = A @ Bt^T (+bias on cols<256) ======
// 128x128 tile, BK=64, 4 waves (2x2). ldc = C row stride. grid.x = N/128.
template <bool BIAS>
__global__ __launch_bounds__(256) void k_gemm_mfma(const bf16* __restrict__ A,
                                                   const bf16* __restrict__ Bt,
                                                   bf16* __restrict__ C, int M, int ldc,
                                                   const float* __restrict__ bias256) {
    __shared__ bf16 As[128 * 64];
    __shared__ bf16 Bs[128 * 64];
    const int tid = threadIdx.x;
    const int lane = tid & 63;
    const int w = tid >> 6;
    const int wr = w >> 1, wc = w & 1;
    const int lr = lane & 15, quad = lane >> 4;
    const int row0 = blockIdx.y * 128;
    const int col0 = blockIdx.x * 128;

    f32x4_t acc[4][4] = {};

    for (int k0 = 0; k0 < 256; k0 += 64) {
#pragma unroll
        for (int i = 0; i < 4; ++i) {
            int j = i * 256 + tid;
            int r = j >> 3, c = j & 7;
            int gk = ((c ^ (r & 7)) << 3);
            int gr = row0 + r; gr = gr < M ? gr : M - 1;
            async_copy16(A + (size_t)gr * 256 + k0 + gk, (void*)(As + j * 8));
            async_copy16(Bt + (size_t)(col0 + r) * 256 + k0 + gk, (void*)(Bs + j * 8));
        }
        __syncthreads();
#pragma unroll
        for (int ks = 0; ks < 2; ++ks) {
            bf16x8_t af[4], bfr[4];
#pragma unroll
            for (int mi = 0; mi < 4; ++mi) {
                int m = wr * 64 + mi * 16 + lr;
                int c = (ks * 4 + quad) ^ (m & 7);
                af[mi] = *(const bf16x8_t*)(As + m * 64 + c * 8);
            }
#pragma unroll
            for (int ni = 0; ni < 4; ++ni) {
                int n = wc * 64 + ni * 16 + lr;
                int c = (ks * 4 + quad) ^ (n & 7);
                bfr[ni] = *(const bf16x8_t*)(Bs + n * 64 + c * 8);
            }
#pragma unroll
            for (int mi = 0; mi < 4; ++mi)
#pragma unroll
                for (int ni = 0; ni < 4; ++ni)
                    acc[mi][ni] = __builtin_amdgcn_mfma_f32_16x16x32_bf16(
                        af[mi], bfr[ni], acc[mi][ni], 0, 0, 0);
        }
        __syncthreads();
    }
    float bv[4];
#pragma unroll
    for (int ni = 0; ni < 4; ++ni) {
        int colg = col0 + wc * 64 + ni * 16 + lr;
        bv[ni] = (BIAS && colg < 256) ? bias256[colg] : 0.f;
    }
#pragma unroll
    for (int mi = 0; mi < 4; ++mi) {
#pragma unroll
        for (int r = 0; r < 4; ++r) {
            int row = row0 + wr * 64 + mi * 16 + quad * 4 + r;
            if (row < M) {
#pragma unroll
                for (int ni = 0; ni < 4; ++ni) {
                    int colg = col0 + wc * 64 + ni * 16 + lr;
                    store_val(C + (size_t)row * ldc + colg, acc[mi][ni][r] + bv[ni]);
                }
            }
        }
    }
}

// ===== CSR aggregation, 16 nodes/block, precomputed edge weights, 2-way unrolled =====
// STATS: part[blockIdx][c] = sum over block's 16 nodes (c<256: sum; c>=256: sumsq), fp32.
template <bool STATS>
__global__ __launch_bounds__(256) void k_agg_csr(const unsigned short* __restrict__ xw,
                                                 const int* __restrict__ row_ptr,
                                                 const int* __restrict__ col,
                                                 const float* __restrict__ wedge,
                                                 const float* __restrict__ dinv,
                                                 const float* __restrict__ bias,
                                                 bf16* __restrict__ out,
                                                 float* __restrict__ part) {
    __shared__ float sred[4][256];
    __shared__ float qred[4][256];
    int w = threadIdx.x >> 6, lane = threadIdx.x & 63;
    int base = blockIdx.x * 16 + w * 4;  // exact: AGG_BLOCKS*16 == N_NODES
    const ushort4* xwv = (const ushort4*)xw;
    float4 bv = ((const float4*)bias)[lane];
    float4 s4 = make_float4(0.f, 0.f, 0.f, 0.f);
    float4 q4 = make_float4(0.f, 0.f, 0.f, 0.f);
#pragma unroll
    for (int n = 0; n < 4; ++n) {
        int node = base + n;
        int beg = row_ptr[node], end = row_ptr[node + 1];
        float dv = dinv[node];
        ushort4 xr = xwv[(size_t)node * 64 + lane];
        float s2 = dv * dv;
        float4 acc;
        acc.x = s2 * bf2f(xr.x); acc.y = s2 * bf2f(xr.y);
        acc.z = s2 * bf2f(xr.z); acc.w = s2 * bf2f(xr.w);
        int i = beg;
        for (; i + 2 <= end; i += 2) {  // 2 outstanding gathers
            int sa = col[i], sb = col[i + 1];
            float wa = wedge[i], wb = wedge[i + 1];
            ushort4 ma = xwv[(size_t)sa * 64 + lane];
            ushort4 mb = xwv[(size_t)sb * 64 + lane];
            acc.x += wa * bf2f(ma.x) + wb * bf2f(mb.x);
            acc.y += wa * bf2f(ma.y) + wb * bf2f(mb.y);
            acc.z += wa * bf2f(ma.z) + wb * bf2f(mb.z);
            acc.w += wa * bf2f(ma.w) + wb * bf2f(mb.w);
        }
        if (i < end) {
            int sa = col[i];
            float wa = wedge[i];
            ushort4 ma = xwv[(size_t)sa * 64 + lane];
            acc.x += wa * bf2f(ma.x); acc.y += wa * bf2f(ma.y);
            acc.z += wa * bf2f(ma.z); acc.w += wa * bf2f(ma.w);
        }
        acc.x += bv.x; acc.y += bv.y; acc.z += bv.z; acc.w += bv.w;
        store4(out + (size_t)node * CH + lane * 4, acc);
        if (STATS) {
            s4.x += acc.x; s4.y += acc.y; s4.z += acc.z; s4.w += acc.w;
            q4.x += acc.x * acc.x; q4.y += acc.y * acc.y;
            q4.z += acc.z * acc.z; q4.w += acc.w * acc.w;
        }
    }
    if (STATS) {
        *(float4*)(&sred[w][lane * 4]) = s4;
        *(float4*)(&qred[w][lane * 4]) = q4;
        __syncthreads();
        if (w == 0) {
#pragma unroll
            for (int g = 1; g < 4; ++g) {
                float4 sg = *(float4*)(&sred[g][lane * 4]);
                float4 qg = *(float4*)(&qred[g][lane * 4]);
                s4.x += sg.x; s4.y += sg.y; s4.z += sg.z; s4.w += sg.w;
                q4.x += qg.x; q4.y += qg.y; q4.z += qg.z; q4.w += qg.w;
            }
            float* p = part + (size_t)blockIdx.x * 512;
            *(float4*)(p + lane * 4) = s4;
            *(float4*)(p + 256 + lane * 4) = q4;
        }
    }
}

// one wave per channel: lanes stride over AGG_BLOCKS partials, shuffle-reduce
__global__ __launch_bounds__(256) void k_bn_finalize(const float* __restrict__ part,
                                                     const float* __restrict__ g,
                                                     const float* __restrict__ be,
                                                     float* __restrict__ scale,
                                                     float* __restrict__ shift) {
    int wave = threadIdx.x >> 6, lane = threadIdx.x & 63;
    int c = blockIdx.x * 4 + wave;  // 0..255
    float s = 0.f, q = 0.f;
    for (int j = lane; j < AGG_BLOCKS; j += 64) {
        s += part[(size_t)j * 512 + c];
        q += part[(size_t)j * 512 + 256 + c];
    }
#pragma unroll
    for (int off = 32; off > 0; off >>= 1) {
        s += __shfl_down(s, off, 64);
        q += __shfl_down(q, off, 64);
    }
    if (lane == 0) {
        float mu = s * (1.0f / N_NODES);
        float var = q * (1.0f / N_NODES) - mu * mu;
        float sc = g[c] * rsqrtf(var + EPS);
        scale[c] = sc;
        shift[c] = be[c] - mu * sc;
    }
}

// ======= edge scoring: 2 edges/wave, 32 lanes each, 8 ch/lane; fc1_b pre-added to u =======
__global__ __launch_bounds__(256) void k_edge_score(
        const unsigned short* __restrict__ uv,
        const int* __restrict__ src, const int* __restrict__ dst,
        const int* __restrict__ neg,
        const float* __restrict__ fc2_w, const float* __restrict__ fc2_b,
        float* __restrict__ out) {
    int wave = threadIdx.x >> 6, lane = threadIdx.x & 63;
    int half = lane >> 5, l = lane & 31;
    int e = blockIdx.x * 8 + wave * 2 + half;
    if (e >= N_EDGES) return;
    int s = src[e], d = dst[e], g = neg[e];
    uint4 uu = ((const uint4*)(uv + (size_t)s * 512))[l];
    uint4 vp = ((const uint4*)(uv + (size_t)d * 512 + 256))[l];
    uint4 vn = ((const uint4*)(uv + (size_t)g * 512 + 256))[l];
    float4 w0 = ((const float4*)fc2_w)[l * 2];
    float4 w1 = ((const float4*)fc2_w)[l * 2 + 1];

    float t0 = bflo(uu.x), t1 = bfhi(uu.x);
    float t2 = bflo(uu.y), t3 = bfhi(uu.y);
    float t4 = bflo(uu.z), t5 = bfhi(uu.z);
    float t6 = bflo(uu.w), t7 = bfhi(uu.w);

    float accp = fmaxf(t0 + bflo(vp.x), 0.f) * w0.x + fmaxf(t1 + bfhi(vp.x), 0.f) * w0.y +
                 fmaxf(t2 + bflo(vp.y), 0.f) * w0.z + fmaxf(t3 + bfhi(vp.y), 0.f) * w0.w +
                 fmaxf(t4 + bflo(vp.z), 0.f) * w1.x + fmaxf(t5 + bfhi(vp.z), 0.f) * w1.y +
                 fmaxf(t6 + bflo(vp.w), 0.f) * w1.z + fmaxf(t7 + bfhi(vp.w), 0.f) * w1.w;
    float accn = fmaxf(t0 + bflo(vn.x), 0.f) * w0.x + fmaxf(t1 + bfhi(vn.x), 0.f) * w0.y +
                 fmaxf(t2 + bflo(vn.y), 0.f) * w0.z + fmaxf(t3 + bfhi(vn.y), 0.f) * w0.w +
                 fmaxf(t4 + bflo(vn.z), 0.f) * w1.x + fmaxf(t5 + bfhi(vn.z), 0.f) * w1.y +
                 fmaxf(t6 + bflo(vn.w), 0.f) * w1.z + fmaxf(t7 + bfhi(vn.w), 0.f) * w1.w;
#pragma unroll
    for (int off = 16; off > 0; off >>= 1) {
        accp += __shfl_down(accp, off, 64);
        accn += __shfl_down(accn, off, 64);
    }
    if (l == 0) {
        float bb = fc2_b[0];
        out[e] = 1.0f / (1.0f + expf(-(accp + bb)));
        out[N_EDGES + e] = 1.0f / (1.0f + expf(-(accn + bb)));
    }
}

extern "C" void kernel_launch(void* const* d_in, const int* in_sizes, int n_in,
                              void* d_out, int out_size, void* d_ws, size_t ws_size,
                              hipStream_t stream) {
    const float* node_feat = (const float*)d_in[0];
    const int* src = (const int*)d_in[1];
    const int* dst = (const int*)d_in[2];
    const int* neg = (const int*)d_in[3];
    const float* W1 = (const float*)d_in[4];  const float* b1 = (const float*)d_in[5];
    const float* W2 = (const float*)d_in[6];  const float* b2 = (const float*)d_in[7];
    const float* W3 = (const float*)d_in[8];  const float* b3 = (const float*)d_in[9];
    const float* g1 = (const float*)d_in[10]; const float* be1 = (const float*)d_in[11];
    const float* g2 = (const float*)d_in[12]; const float* be2 = (const float*)d_in[13];
    const float* fc1_w = (const float*)d_in[14]; const float* fc1_b = (const float*)d_in[15];
    const float* fc2_w = (const float*)d_in[16]; const float* fc2_b = (const float*)d_in[17];
    float* out = (float*)d_out;

    // ---- workspace layout (~222 MB total) ----
    const size_t NF = (size_t)N_NODES * CH;  // 25,600,000
    bf16* UV = (bf16*)d_ws;                  // [node][512] u|v (2*NF)
    bf16* Xbf = UV + 2 * NF;                 // bf16 activations / agg out / z (NF)
    bf16* XwBf = Xbf + NF;                   // bf16 GEMM output xw (NF)
    bf16* wt = XwBf + NF;                    // 5 * 65536 (wt1,wt2,wt3,wtu,wtv)
    float* dinv = (float*)(wt + 5 * 65536);
    float* bnpart = dinv + N_NODES;          // AGG_BLOCKS * 512 (12.8 MB)
    float* scale = bnpart + (size_t)AGG_BLOCKS * 512;
    float* shift = scale + CH;
    float* wedge = shift + CH;               // E floats (1.2 MB)
    int* ideg = (int*)(wedge + N_EDGES);     // N (cursor follows: zeroed together)
    int* cursor = ideg + N_NODES;
    int* row_ptr = cursor + N_NODES;
    int* col = row_ptr + N_NODES + 1;
    int* bsum = col + N_EDGES;               // 512
    (void)ws_size;

    dim3 gemmGrid(2, (N_NODES + 127) / 128);   // 2 x 782
    dim3 uvGrid(4, (N_NODES + 127) / 128);     // 4 x 782 (N=512)
    int nodeBlocks = (N_NODES + 255) / 256;    // 391
    int edgeBlocks = (N_EDGES + 255) / 256;
    int v4Blocks = (int)(NF / 4 / 256);        // 25000
    int scoreBlocks = (N_EDGES + 7) / 8;       // 37500

    // ---- CSR build + dinv + edge weights ----
    k_zero_int<<<(2 * N_NODES + 255) / 256, 256, 0, stream>>>(ideg, 2 * N_NODES);
    k_count_deg<<<edgeBlocks, 256, 0, stream>>>(dst, ideg);
    k_dinv_from_deg<<<nodeBlocks, 256, 0, stream>>>(ideg, dinv);
    k_block_sums<<<nodeBlocks, 256, 0, stream>>>(ideg, bsum);
    k_scan_bsums<<<1, 512, 0, stream>>>(bsum, nodeBlocks);
    k_row_ptr<<<nodeBlocks, 256, 0, stream>>>(ideg, bsum, row_ptr);
    k_scatter<<<edgeBlocks, 256, 0, stream>>>(src, dst, row_ptr, cursor, dinv, col, wedge);

    // ---- all weight transposes ----
    k_transpose_all<<<1280, 256, 0, stream>>>(W1, W2, W3, fc1_w, wt);

    // ---- layer 1 ----
    k_cast_bf16_v4<<<v4Blocks, 256, 0, stream>>>(node_feat, (unsigned short*)Xbf);
    k_gemm_mfma<false><<<gemmGrid, 256, 0, stream>>>(Xbf, wt, XwBf, N_NODES, 256, nullptr);
    k_agg_csr<true><<<AGG_BLOCKS, 256, 0, stream>>>((unsigned short*)XwBf, row_ptr, col,
                                                    wedge, dinv, b1, Xbf, bnpart);
    k_bn_finalize<<<64, 256, 0, stream>>>(bnpart, g1, be1, scale, shift);
    k_bn_relu_bf16<<<v4Blocks, 256, 0, stream>>>((unsigned short*)Xbf, scale, shift);

    // ---- layer 2 ----
    k_gemm_mfma<false><<<gemmGrid, 256, 0, stream>>>(Xbf, wt + 65536, XwBf, N_NODES, 256, nullptr);
    k_agg_csr<true><<<AGG_BLOCKS, 256, 0, stream>>>((unsigned short*)XwBf, row_ptr, col,
                                                    wedge, dinv, b2, Xbf, bnpart);
    k_bn_finalize<<<64, 256, 0, stream>>>(bnpart, g2, be2, scale, shift);
    k_bn_relu_bf16<<<v4Blocks, 256, 0, stream>>>((unsigned short*)Xbf, scale, shift);

    // ---- layer 3: agg writes z (bf16) into Xbf ----
    k_gemm_mfma<false><<<gemmGrid, 256, 0, stream>>>(Xbf, wt + 2 * 65536, XwBf, N_NODES, 256, nullptr);
    k_agg_csr<false><<<AGG_BLOCKS, 256, 0, stream>>>((unsigned short*)XwBf, row_ptr, col,
                                                     wedge, dinv, b3, Xbf, nullptr);

    // ---- link predictor: UV = z @ [wtu|wtv]^T + [fc1_b|0] ----
    k_gemm_mfma<true><<<uvGrid, 256, 0, stream>>>(Xbf, wt + 3 * 65536, UV, N_NODES, 512, fc1_b);
    k_edge_score<<<scoreBlocks, 256, 0, stream>>>((unsigned short*)UV, src, dst, neg,
                                                  fc2_w, fc2_b, out);
}

// Round 12
// 615.016 us; speedup vs baseline: 1.1922x; 1.1370x over previous
//
#include <hip/hip_runtime.h>
#include <hip/hip_bf16.h>

#define N_NODES 100000
#define N_EDGES 300000
#define CH 256
#define EPS 1e-5f
#define AGG_BLOCKS 3125   // N_NODES / 32 exactly
#define Y_TILES 782       // ceil(N_NODES/128)
#define Y_TILES_PAD 784   // padded to multiple of 8

typedef __hip_bfloat16 bf16;
typedef __attribute__((ext_vector_type(8))) short bf16x8_t;  // 8 bf16 (4 VGPRs)
typedef __attribute__((ext_vector_type(4))) float f32x4_t;   // 4 fp32 acc

__device__ __forceinline__ unsigned short f2bf(float f) {
    bf16 h = __float2bfloat16(f);
    return __builtin_bit_cast(unsigned short, h);
}
__device__ __forceinline__ float bf2f(unsigned short u) {
    unsigned int x = ((unsigned int)u) << 16;  // exact widening
    return __builtin_bit_cast(float, x);
}
__device__ __forceinline__ float bflo(unsigned int w) {
    return __builtin_bit_cast(float, w << 16);
}
__device__ __forceinline__ float bfhi(unsigned int w) {
    return __builtin_bit_cast(float, w & 0xffff0000u);
}
__device__ __forceinline__ unsigned pack2(float a, float b) {
    return (unsigned)f2bf(a) | ((unsigned)f2bf(b) << 16);
}
__device__ __forceinline__ void store_val(bf16* p, float v) { *p = __float2bfloat16(v); }

__device__ __forceinline__ void async_copy16(const void* g, void* l) {
    __builtin_amdgcn_global_load_lds((const __attribute__((address_space(1))) void*)g,
                                     (__attribute__((address_space(3))) void*)l, 16, 0, 0);
}

// ================= CSR build =================
__global__ void k_zero_int(int* __restrict__ p, int n) {
    int i = blockIdx.x * 256 + threadIdx.x;
    if (i < n) p[i] = 0;
}
__global__ void k_count_deg(const int* __restrict__ dst, int* __restrict__ deg) {
    int e = blockIdx.x * 256 + threadIdx.x;
    if (e < N_EDGES) atomicAdd(&deg[dst[e]], 1);
}
__global__ void k_dinv_from_deg(const int* __restrict__ deg, float* __restrict__ dinv) {
    int i = blockIdx.x * 256 + threadIdx.x;
    if (i < N_NODES) dinv[i] = rsqrtf((float)(deg[i] + 1));  // +1 self loop
}
__global__ void k_block_sums(const int* __restrict__ deg, int* __restrict__ bsum) {
    __shared__ int s[256];
    int t = threadIdx.x;
    int i = blockIdx.x * 256 + t;
    s[t] = (i < N_NODES) ? deg[i] : 0;
    __syncthreads();
    for (int off = 128; off > 0; off >>= 1) {
        if (t < off) s[t] += s[t + off];
        __syncthreads();
    }
    if (t == 0) bsum[blockIdx.x] = s[0];
}
__global__ void k_scan_bsums(int* __restrict__ bsum, int nb) {
    __shared__ int s[512];
    int t = threadIdx.x;
    int v = (t < nb) ? bsum[t] : 0;
    s[t] = v;
    __syncthreads();
    for (int off = 1; off < 512; off <<= 1) {
        int u = (t >= off) ? s[t - off] : 0;
        __syncthreads();
        s[t] += u;
        __syncthreads();
    }
    if (t < nb) bsum[t] = s[t] - v;  // exclusive
}
__global__ void k_row_ptr(const int* __restrict__ deg, const int* __restrict__ bsum,
                          int* __restrict__ row_ptr) {
    __shared__ int s[256];
    int t = threadIdx.x;
    int i = blockIdx.x * 256 + t;
    int v = (i < N_NODES) ? deg[i] : 0;
    s[t] = v;
    __syncthreads();
    for (int off = 1; off < 256; off <<= 1) {
        int u = (t >= off) ? s[t - off] : 0;
        __syncthreads();
        s[t] += u;
        __syncthreads();
    }
    if (i < N_NODES) row_ptr[i] = bsum[blockIdx.x] + s[t] - v;  // exclusive
    if (blockIdx.x == 0 && t == 0) row_ptr[N_NODES] = N_EDGES;
}
// scatter also precomputes per-edge weight wedge = dinv[d]*dinv[s]
__global__ void k_scatter(const int* __restrict__ src, const int* __restrict__ dst,
                          const int* __restrict__ row_ptr, int* __restrict__ cursor,
                          const float* __restrict__ dinv,
                          int* __restrict__ col, float* __restrict__ wedge) {
    int e = blockIdx.x * 256 + threadIdx.x;
    if (e < N_EDGES) {
        int d = dst[e], s = src[e];
        int p = atomicAdd(&cursor[d], 1);
        int idx = row_ptr[d] + p;
        col[idx] = s;
        wedge[idx] = dinv[d] * dinv[s];
    }
}

// ================= all weight transposes in one kernel =================
__global__ void k_transpose_all(const float* __restrict__ W1, const float* __restrict__ W2,
                                const float* __restrict__ W3, const float* __restrict__ fc1w,
                                bf16* __restrict__ wt) {
    int which = blockIdx.x >> 8;  // 0..4
    int idx = ((blockIdx.x & 255) << 8) + threadIdx.x;
    int n = idx >> 8, k = idx & 255;
    const float* W; int ro = 0;
    switch (which) {
        case 0: W = W1; break;
        case 1: W = W2; break;
        case 2: W = W3; break;
        case 3: W = fc1w; break;
        default: W = fc1w; ro = 256; break;
    }
    wt[(size_t)which * 65536 + (size_t)n * 256 + k] =
        __float2bfloat16(W[(size_t)(ro + k) * 256 + n]);
}

// ================= casts =================
__global__ void k_cast_bf16_v4(const float* __restrict__ x, unsigned short* __restrict__ y) {
    int i = blockIdx.x * 256 + threadIdx.x;  // over NF/4
    float4 v = ((const float4*)x)[i];
    ushort4 o;
    o.x = f2bf(v.x); o.y = f2bf(v.y); o.z = f2bf(v.z); o.w = f2bf(v.w);
    ((ushort4*)y)[i] = o;
}
// in-place BN apply + relu on bf16 buffer
__global__ void k_bn_relu_bf16(unsigned short* __restrict__ x, const float* __restrict__ scale,
                               const float* __restrict__ shift) {
    int i = blockIdx.x * 256 + threadIdx.x;  // over NF/4
    ushort4 m = ((ushort4*)x)[i];
    int c = (i & 63) * 4;
    float4 sc = *(const float4*)(scale + c);
    float4 sh = *(const float4*)(shift + c);
    ushort4 o;
    o.x = f2bf(fmaxf(bf2f(m.x) * sc.x + sh.x, 0.f));
    o.y = f2bf(fmaxf(bf2f(m.y) * sc.y + sh.y, 0.f));
    o.z = f2bf(fmaxf(bf2f(m.z) * sc.z + sh.z, 0.f));
    o.w = f2bf(fmaxf(bf2f(m.w) * sc.w + sh.w, 0.f));
    ((ushort4*)x)[i] = o;
}

// ====== bf16 MFMA GEMM (async staged, XCD-swizzled tiles) ======
// C[M x (NX*128)] = A @ Bt^T (+bias on cols<256). 128x128 tile, BK=64, 4 waves.
// 1-D grid of NX*Y_TILES_PAD blocks; tiles sharing a row-tile map to the same XCD
// (indices differ by 8 -> same round-robin XCD) so the A-tile hits L2 once.
template <int NX, bool BIAS>
__global__ __launch_bounds__(256) void k_gemm_mfma(const bf16* __restrict__ A,
                                                   const bf16* __restrict__ Bt,
                                                   bf16* __restrict__ C, int M, int ldc,
                                                   const float* __restrict__ bias256) {
    constexpr int LOG2NX = (NX == 4) ? 2 : 1;
    int id = blockIdx.x;
    int rg = (id & 7) + 8 * (id >> (3 + LOG2NX));
    int ct = (id >> 3) & (NX - 1);
    if (rg >= Y_TILES) return;
    const int row0 = rg * 128;
    const int col0 = ct * 128;

    __shared__ bf16 As[128 * 64];
    __shared__ bf16 Bs[128 * 64];
    const int tid = threadIdx.x;
    const int lane = tid & 63;
    const int w = tid >> 6;
    const int wr = w >> 1, wc = w & 1;
    const int lr = lane & 15, quad = lane >> 4;

    f32x4_t acc[4][4] = {};

    for (int k0 = 0; k0 < 256; k0 += 64) {
#pragma unroll
        for (int i = 0; i < 4; ++i) {
            int j = i * 256 + tid;
            int r = j >> 3, c = j & 7;
            int gk = ((c ^ (r & 7)) << 3);
            int gr = row0 + r; gr = gr < M ? gr : M - 1;
            async_copy16(A + (size_t)gr * 256 + k0 + gk, (void*)(As + j * 8));
            async_copy16(Bt + (size_t)(col0 + r) * 256 + k0 + gk, (void*)(Bs + j * 8));
        }
        __syncthreads();
#pragma unroll
        for (int ks = 0; ks < 2; ++ks) {
            bf16x8_t af[4], bfr[4];
#pragma unroll
            for (int mi = 0; mi < 4; ++mi) {
                int m = wr * 64 + mi * 16 + lr;
                int c = (ks * 4 + quad) ^ (m & 7);
                af[mi] = *(const bf16x8_t*)(As + m * 64 + c * 8);
            }
#pragma unroll
            for (int ni = 0; ni < 4; ++ni) {
                int n = wc * 64 + ni * 16 + lr;
                int c = (ks * 4 + quad) ^ (n & 7);
                bfr[ni] = *(const bf16x8_t*)(Bs + n * 64 + c * 8);
            }
#pragma unroll
            for (int mi = 0; mi < 4; ++mi)
#pragma unroll
                for (int ni = 0; ni < 4; ++ni)
                    acc[mi][ni] = __builtin_amdgcn_mfma_f32_16x16x32_bf16(
                        af[mi], bfr[ni], acc[mi][ni], 0, 0, 0);
        }
        __syncthreads();
    }
    float bv[4];
#pragma unroll
    for (int ni = 0; ni < 4; ++ni) {
        int colg = col0 + wc * 64 + ni * 16 + lr;
        bv[ni] = (BIAS && colg < 256) ? bias256[colg] : 0.f;
    }
#pragma unroll
    for (int mi = 0; mi < 4; ++mi) {
#pragma unroll
        for (int r = 0; r < 4; ++r) {
            int row = row0 + wr * 64 + mi * 16 + quad * 4 + r;
            if (row < M) {
#pragma unroll
                for (int ni = 0; ni < 4; ++ni) {
                    int colg = col0 + wc * 64 + ni * 16 + lr;
                    store_val(C + (size_t)row * ldc + colg, acc[mi][ni][r] + bv[ni]);
                }
            }
        }
    }
}

// ===== CSR aggregation: 32 lanes/node (uint4=8ch per lane), 32 nodes/block =====
// STATS: part[blockIdx][c] = sum over block's 32 nodes (c<256: sum; c>=256: sumsq).
template <bool STATS>
__global__ __launch_bounds__(256) void k_agg_csr(const unsigned short* __restrict__ xw,
                                                 const int* __restrict__ row_ptr,
                                                 const int* __restrict__ col,
                                                 const float* __restrict__ wedge,
                                                 const float* __restrict__ dinv,
                                                 const float* __restrict__ bias,
                                                 bf16* __restrict__ out,
                                                 float* __restrict__ part) {
    __shared__ float sred[8][256];
    __shared__ float qred[8][256];
    int g = threadIdx.x >> 5, lh = threadIdx.x & 31;  // 8 half-waves x 32 lanes
    int base = blockIdx.x * 32 + g * 4;               // exact: AGG_BLOCKS*32 == N_NODES
    const uint4* xwv = (const uint4*)xw;              // bf16 row = 32 uint4
    float4 b0 = ((const float4*)bias)[lh * 2];
    float4 b1 = ((const float4*)bias)[lh * 2 + 1];
    float s8[8] = {}, q8[8] = {};
#pragma unroll
    for (int n = 0; n < 4; ++n) {
        int node = base + n;
        int beg = row_ptr[node], end = row_ptr[node + 1];
        float dv = dinv[node];
        uint4 xr = xwv[(size_t)node * 32 + lh];
        float s2 = dv * dv;
        float a0 = s2 * bflo(xr.x), a1 = s2 * bfhi(xr.x);
        float a2 = s2 * bflo(xr.y), a3 = s2 * bfhi(xr.y);
        float a4 = s2 * bflo(xr.z), a5 = s2 * bfhi(xr.z);
        float a6 = s2 * bflo(xr.w), a7 = s2 * bfhi(xr.w);
        int i = beg;
        for (; i + 2 <= end; i += 2) {  // 2 outstanding gathers per chain
            int sa = col[i], sb = col[i + 1];
            float wa = wedge[i], wb = wedge[i + 1];
            uint4 ma = xwv[(size_t)sa * 32 + lh];
            uint4 mb = xwv[(size_t)sb * 32 + lh];
            a0 += wa * bflo(ma.x) + wb * bflo(mb.x);
            a1 += wa * bfhi(ma.x) + wb * bfhi(mb.x);
            a2 += wa * bflo(ma.y) + wb * bflo(mb.y);
            a3 += wa * bfhi(ma.y) + wb * bfhi(mb.y);
            a4 += wa * bflo(ma.z) + wb * bflo(mb.z);
            a5 += wa * bfhi(ma.z) + wb * bfhi(mb.z);
            a6 += wa * bflo(ma.w) + wb * bflo(mb.w);
            a7 += wa * bfhi(ma.w) + wb * bfhi(mb.w);
        }
        if (i < end) {
            int sa = col[i];
            float wa = wedge[i];
            uint4 ma = xwv[(size_t)sa * 32 + lh];
            a0 += wa * bflo(ma.x); a1 += wa * bfhi(ma.x);
            a2 += wa * bflo(ma.y); a3 += wa * bfhi(ma.y);
            a4 += wa * bflo(ma.z); a5 += wa * bfhi(ma.z);
            a6 += wa * bflo(ma.w); a7 += wa * bfhi(ma.w);
        }
        a0 += b0.x; a1 += b0.y; a2 += b0.z; a3 += b0.w;
        a4 += b1.x; a5 += b1.y; a6 += b1.z; a7 += b1.w;
        uint4 o;
        o.x = pack2(a0, a1); o.y = pack2(a2, a3);
        o.z = pack2(a4, a5); o.w = pack2(a6, a7);
        ((uint4*)(out + (size_t)node * CH))[lh] = o;
        if (STATS) {
            s8[0] += a0; s8[1] += a1; s8[2] += a2; s8[3] += a3;
            s8[4] += a4; s8[5] += a5; s8[6] += a6; s8[7] += a7;
            q8[0] += a0 * a0; q8[1] += a1 * a1; q8[2] += a2 * a2; q8[3] += a3 * a3;
            q8[4] += a4 * a4; q8[5] += a5 * a5; q8[6] += a6 * a6; q8[7] += a7 * a7;
        }
    }
    if (STATS) {
#pragma unroll
        for (int j = 0; j < 8; ++j) {
            sred[g][lh * 8 + j] = s8[j];
            qred[g][lh * 8 + j] = q8[j];
        }
        __syncthreads();
        int t = threadIdx.x;  // channel 0..255
        float ss = 0.f, qq = 0.f;
#pragma unroll
        for (int gg = 0; gg < 8; ++gg) {
            ss += sred[gg][t];
            qq += qred[gg][t];
        }
        part[(size_t)blockIdx.x * 512 + t] = ss;
        part[(size_t)blockIdx.x * 512 + 256 + t] = qq;
    }
}

// one wave per channel: lanes stride over AGG_BLOCKS partials, shuffle-reduce
__global__ __launch_bounds__(256) void k_bn_finalize(const float* __restrict__ part,
                                                     const float* __restrict__ g,
                                                     const float* __restrict__ be,
                                                     float* __restrict__ scale,
                                                     float* __restrict__ shift) {
    int wave = threadIdx.x >> 6, lane = threadIdx.x & 63;
    int c = blockIdx.x * 4 + wave;  // 0..255
    float s = 0.f, q = 0.f;
    for (int j = lane; j < AGG_BLOCKS; j += 64) {
        s += part[(size_t)j * 512 + c];
        q += part[(size_t)j * 512 + 256 + c];
    }
#pragma unroll
    for (int off = 32; off > 0; off >>= 1) {
        s += __shfl_down(s, off, 64);
        q += __shfl_down(q, off, 64);
    }
    if (lane == 0) {
        float mu = s * (1.0f / N_NODES);
        float var = q * (1.0f / N_NODES) - mu * mu;
        float sc = g[c] * rsqrtf(var + EPS);
        scale[c] = sc;
        shift[c] = be[c] - mu * sc;
    }
}

// ======= edge scoring: 4 edges/wave, 16 lanes each, 16 ch/lane; fc1_b pre-added to u =======
__global__ __launch_bounds__(256) void k_edge_score(
        const unsigned short* __restrict__ uv,
        const int* __restrict__ src, const int* __restrict__ dst,
        const int* __restrict__ neg,
        const float* __restrict__ fc2_w, const float* __restrict__ fc2_b,
        float* __restrict__ out) {
    int wave = threadIdx.x >> 6, lane = threadIdx.x & 63;
    int qtr = lane >> 4, l = lane & 15;
    int e = blockIdx.x * 16 + wave * 4 + qtr;
    if (e >= N_EDGES) return;
    int s = src[e], d = dst[e], g = neg[e];
    const uint4* uvv = (const uint4*)uv;  // row = 64 uint4 (u: 0..31, v: 32..63)
    uint4 u0 = uvv[(size_t)s * 64 + l * 2];
    uint4 u1 = uvv[(size_t)s * 64 + l * 2 + 1];
    uint4 p0 = uvv[(size_t)d * 64 + 32 + l * 2];
    uint4 p1 = uvv[(size_t)d * 64 + 32 + l * 2 + 1];
    uint4 n0 = uvv[(size_t)g * 64 + 32 + l * 2];
    uint4 n1 = uvv[(size_t)g * 64 + 32 + l * 2 + 1];
    float4 w0 = ((const float4*)fc2_w)[l * 4];
    float4 w1 = ((const float4*)fc2_w)[l * 4 + 1];
    float4 w2 = ((const float4*)fc2_w)[l * 4 + 2];
    float4 w3 = ((const float4*)fc2_w)[l * 4 + 3];

    float t0 = bflo(u0.x), t1 = bfhi(u0.x), t2 = bflo(u0.y), t3 = bfhi(u0.y);
    float t4 = bflo(u0.z), t5 = bfhi(u0.z), t6 = bflo(u0.w), t7 = bfhi(u0.w);
    float t8 = bflo(u1.x), t9 = bfhi(u1.x), ta = bflo(u1.y), tb = bfhi(u1.y);
    float tc = bflo(u1.z), td = bfhi(u1.z), te = bflo(u1.w), tf = bfhi(u1.w);

    float accp =
        fmaxf(t0 + bflo(p0.x), 0.f) * w0.x + fmaxf(t1 + bfhi(p0.x), 0.f) * w0.y +
        fmaxf(t2 + bflo(p0.y), 0.f) * w0.z + fmaxf(t3 + bfhi(p0.y), 0.f) * w0.w +
        fmaxf(t4 + bflo(p0.z), 0.f) * w1.x + fmaxf(t5 + bfhi(p0.z), 0.f) * w1.y +
        fmaxf(t6 + bflo(p0.w), 0.f) * w1.z + fmaxf(t7 + bfhi(p0.w), 0.f) * w1.w +
        fmaxf(t8 + bflo(p1.x), 0.f) * w2.x + fmaxf(t9 + bfhi(p1.x), 0.f) * w2.y +
        fmaxf(ta + bflo(p1.y), 0.f) * w2.z + fmaxf(tb + bfhi(p1.y), 0.f) * w2.w +
        fmaxf(tc + bflo(p1.z), 0.f) * w3.x + fmaxf(td + bfhi(p1.z), 0.f) * w3.y +
        fmaxf(te + bflo(p1.w), 0.f) * w3.z + fmaxf(tf + bfhi(p1.w), 0.f) * w3.w;
    float accn =
        fmaxf(t0 + bflo(n0.x), 0.f) * w0.x + fmaxf(t1 + bfhi(n0.x), 0.f) * w0.y +
        fmaxf(t2 + bflo(n0.y), 0.f) * w0.z + fmaxf(t3 + bfhi(n0.y), 0.f) * w0.w +
        fmaxf(t4 + bflo(n0.z), 0.f) * w1.x + fmaxf(t5 + bfhi(n0.z), 0.f) * w1.y +
        fmaxf(t6 + bflo(n0.w), 0.f) * w1.z + fmaxf(t7 + bfhi(n0.w), 0.f) * w1.w +
        fmaxf(t8 + bflo(n1.x), 0.f) * w2.x + fmaxf(t9 + bfhi(n1.x), 0.f) * w2.y +
        fmaxf(ta + bflo(n1.y), 0.f) * w2.z + fmaxf(tb + bfhi(n1.y), 0.f) * w2.w +
        fmaxf(tc + bflo(n1.z), 0.f) * w3.x + fmaxf(td + bfhi(n1.z), 0.f) * w3.y +
        fmaxf(te + bflo(n1.w), 0.f) * w3.z + fmaxf(tf + bfhi(n1.w), 0.f) * w3.w;
#pragma unroll
    for (int off = 8; off > 0; off >>= 1) {
        accp += __shfl_down(accp, off, 64);
        accn += __shfl_down(accn, off, 64);
    }
    if (l == 0) {
        float bb = fc2_b[0];
        out[e] = 1.0f / (1.0f + expf(-(accp + bb)));
        out[N_EDGES + e] = 1.0f / (1.0f + expf(-(accn + bb)));
    }
}

extern "C" void kernel_launch(void* const* d_in, const int* in_sizes, int n_in,
                              void* d_out, int out_size, void* d_ws, size_t ws_size,
                              hipStream_t stream) {
    const float* node_feat = (const float*)d_in[0];
    const int* src = (const int*)d_in[1];
    const int* dst = (const int*)d_in[2];
    const int* neg = (const int*)d_in[3];
    const float* W1 = (const float*)d_in[4];  const float* b1 = (const float*)d_in[5];
    const float* W2 = (const float*)d_in[6];  const float* b2 = (const float*)d_in[7];
    const float* W3 = (const float*)d_in[8];  const float* b3 = (const float*)d_in[9];
    const float* g1 = (const float*)d_in[10]; const float* be1 = (const float*)d_in[11];
    const float* g2 = (const float*)d_in[12]; const float* be2 = (const float*)d_in[13];
    const float* fc1_w = (const float*)d_in[14]; const float* fc1_b = (const float*)d_in[15];
    const float* fc2_w = (const float*)d_in[16]; const float* fc2_b = (const float*)d_in[17];
    float* out = (float*)d_out;

    // ---- workspace layout (~215 MB total) ----
    const size_t NF = (size_t)N_NODES * CH;  // 25,600,000
    bf16* UV = (bf16*)d_ws;                  // [node][512] u|v (2*NF)
    bf16* Xbf = UV + 2 * NF;                 // bf16 activations / agg out / z (NF)
    bf16* XwBf = Xbf + NF;                   // bf16 GEMM output xw (NF)
    bf16* wt = XwBf + NF;                    // 5 * 65536 (wt1,wt2,wt3,wtu,wtv)
    float* dinv = (float*)(wt + 5 * 65536);
    float* bnpart = dinv + N_NODES;          // AGG_BLOCKS * 512 (6.4 MB)
    float* scale = bnpart + (size_t)AGG_BLOCKS * 512;
    float* shift = scale + CH;
    float* wedge = shift + CH;               // E floats (1.2 MB)
    int* ideg = (int*)(wedge + N_EDGES);     // N (cursor follows: zeroed together)
    int* cursor = ideg + N_NODES;
    int* row_ptr = cursor + N_NODES;
    int* col = row_ptr + N_NODES + 1;
    int* bsum = col + N_EDGES;               // 512
    (void)ws_size;

    int gemmBlocks = 2 * Y_TILES_PAD;          // 1568 (N=256, NX=2)
    int uvBlocks = 4 * Y_TILES_PAD;            // 3136 (N=512, NX=4)
    int nodeBlocks = (N_NODES + 255) / 256;    // 391
    int edgeBlocks = (N_EDGES + 255) / 256;
    int v4Blocks = (int)(NF / 4 / 256);        // 25000
    int scoreBlocks = (N_EDGES + 15) / 16;     // 18750

    // ---- CSR build + dinv + edge weights ----
    k_zero_int<<<(2 * N_NODES + 255) / 256, 256, 0, stream>>>(ideg, 2 * N_NODES);
    k_count_deg<<<edgeBlocks, 256, 0, stream>>>(dst, ideg);
    k_dinv_from_deg<<<nodeBlocks, 256, 0, stream>>>(ideg, dinv);
    k_block_sums<<<nodeBlocks, 256, 0, stream>>>(ideg, bsum);
    k_scan_bsums<<<1, 512, 0, stream>>>(bsum, nodeBlocks);
    k_row_ptr<<<nodeBlocks, 256, 0, stream>>>(ideg, bsum, row_ptr);
    k_scatter<<<edgeBlocks, 256, 0, stream>>>(src, dst, row_ptr, cursor, dinv, col, wedge);

    // ---- all weight transposes ----
    k_transpose_all<<<1280, 256, 0, stream>>>(W1, W2, W3, fc1_w, wt);

    // ---- layer 1 ----
    k_cast_bf16_v4<<<v4Blocks, 256, 0, stream>>>(node_feat, (unsigned short*)Xbf);
    k_gemm_mfma<2, false><<<gemmBlocks, 256, 0, stream>>>(Xbf, wt, XwBf, N_NODES, 256, nullptr);
    k_agg_csr<true><<<AGG_BLOCKS, 256, 0, stream>>>((unsigned short*)XwBf, row_ptr, col,
                                                    wedge, dinv, b1, Xbf, bnpart);
    k_bn_finalize<<<64, 256, 0, stream>>>(bnpart, g1, be1, scale, shift);
    k_bn_relu_bf16<<<v4Blocks, 256, 0, stream>>>((unsigned short*)Xbf, scale, shift);

    // ---- layer 2 ----
    k_gemm_mfma<2, false><<<gemmBlocks, 256, 0, stream>>>(Xbf, wt + 65536, XwBf, N_NODES, 256, nullptr);
    k_agg_csr<true><<<AGG_BLOCKS, 256, 0, stream>>>((unsigned short*)XwBf, row_ptr, col,
                                                    wedge, dinv, b2, Xbf, bnpart);
    k_bn_finalize<<<64, 256, 0, stream>>>(bnpart, g2, be2, scale, shift);
    k_bn_relu_bf16<<<v4Blocks, 256, 0, stream>>>((unsigned short*)Xbf, scale, shift);

    // ---- layer 3: agg writes z (bf16) into Xbf ----
    k_gemm_mfma<2, false><<<gemmBlocks, 256, 0, stream>>>(Xbf, wt + 2 * 65536, XwBf, N_NODES, 256, nullptr);
    k_agg_csr<false><<<AGG_BLOCKS, 256, 0, stream>>>((unsigned short*)XwBf, row_ptr, col,
                                                     wedge, dinv, b3, Xbf, nullptr);

    // ---- link predictor: UV = z @ [wtu|wtv]^T + [fc1_b|0] ----
    k_gemm_mfma<4, true><<<uvBlocks, 256, 0, stream>>>(Xbf, wt + 3 * 65536, UV, N_NODES, 512, fc1_b);
    k_edge_score<<<scoreBlocks, 256, 0, stream>>>((unsigned short*)UV, src, dst, neg,
                                                  fc2_w, fc2_b, out);
}